// Round 1
// baseline (251.444 us; speedup 1.0000x reference)
//
#include <hip/hip_runtime.h>

// Problem constants (from reference):
//   k_cache/v_cache: [N_PAGES=4096, H=8, PAGE=16, D=128] fp32  (256 MB each)
//   k_val/v_val:     [B=32, S=512, H=8, D=128] fp32            (64 MB each)
//   slot_mapping:    [B, S] int                                 (16384 tokens)
//   out: stack([k_new, v_new]) -> [2, 4096, 8, 16, 128] fp32   (512 MB)

#define NP   4096
#define NH   8
#define PG   16
#define HD   128
#define NTOK (32 * 512)

static constexpr long long CACHE_ELEMS = (long long)NP * NH * PG * HD; // 67,108,864
static constexpr long long CACHE_F4    = CACHE_ELEMS / 4;              // 16,777,216

// Kernel 1: copy both caches into the output (vectorized, grid-stride).
__global__ void pagedkv_copy(const float4* __restrict__ kc,
                             const float4* __restrict__ vc,
                             float4* __restrict__ out) {
    long long i      = (long long)blockIdx.x * blockDim.x + threadIdx.x;
    long long stride = (long long)gridDim.x * blockDim.x;
    float4* __restrict__ outk = out;
    float4* __restrict__ outv = out + CACHE_F4;
    for (; i < CACHE_F4; i += stride) {
        outk[i] = kc[i];
        outv[i] = vc[i];
    }
}

// Kernel 2: scatter token K/V rows into the copied caches.
// One block (256 threads) per token: thread -> (head = tid>>5, d4 = tid&31).
__global__ void pagedkv_scatter(const float4* __restrict__ kv,
                                const float4* __restrict__ vv,
                                const int* __restrict__ slots,
                                float4* __restrict__ out) {
    const int t    = blockIdx.x;
    const int slot = slots[t];
    const int page = slot >> 4;   // slot / PG
    const int off  = slot & 15;   // slot % PG
    const int h    = threadIdx.x >> 5;   // 0..7
    const int d4   = threadIdx.x & 31;   // 0..31  (HD/4 = 32 float4 per row)

    const long long src = ((long long)t * NH + h) * (HD / 4) + d4;
    const long long dst = (((long long)page * NH + h) * PG + off) * (HD / 4) + d4;

    out[dst]            = kv[src];  // K half
    out[CACHE_F4 + dst] = vv[src];  // V half
}

extern "C" void kernel_launch(void* const* d_in, const int* in_sizes, int n_in,
                              void* d_out, int out_size, void* d_ws, size_t ws_size,
                              hipStream_t stream) {
    const float4* kc    = (const float4*)d_in[0];
    const float4* vc    = (const float4*)d_in[1];
    const float4* kv    = (const float4*)d_in[2];
    const float4* vv    = (const float4*)d_in[3];
    const int*    slots = (const int*)d_in[4];
    float4* out = (float4*)d_out;

    // Copy 2 x 256 MB: 2048 blocks x 256 threads, 32 iters of 2 float4 each.
    pagedkv_copy<<<2048, 256, 0, stream>>>(kc, vc, out);
    // Scatter 16384 tokens (same stream -> ordered after the copy).
    pagedkv_scatter<<<NTOK, 256, 0, stream>>>(kv, vv, slots, out);
}

// Round 2
// 226.201 us; speedup vs baseline: 1.1116x; 1.1116x over previous
//
#include <hip/hip_runtime.h>

// Problem constants (from reference):
//   k_cache/v_cache: [N_PAGES=4096, H=8, PAGE=16, D=128] fp32  (256 MB each)
//   k_val/v_val:     [B=32, S=512, H=8, D=128] fp32            (64 MB each)
//   slot_mapping:    [B, S] int                                 (16384 tokens)
//   out: stack([k_new, v_new]) -> [2, 4096, 8, 16, 128] fp32   (512 MB)
//
// Strategy: scatter -> gather inversion. Build slot->token map in d_ws, then
// a single streaming pass writes every output float4 exactly once, reading
// either from the token values (overwritten slots) or the old cache. Saves
// the read of cache rows that get overwritten (~128 MB) and the double-write
// of scattered rows (~128 MB) vs the copy+scatter scheme.

#define NP   4096
#define NH   8
#define PG   16
#define HD   128
#define NTOK (32 * 512)
#define NSLOT (NP * PG)   // 65536

static constexpr long long CACHE_ELEMS = (long long)NP * NH * PG * HD; // 67,108,864
static constexpr long long CACHE_F4    = CACHE_ELEMS / 4;              // 16,777,216

__global__ void pagedkv_init_map(int* __restrict__ map) {
    int i = blockIdx.x * blockDim.x + threadIdx.x;
    if (i < NSLOT) map[i] = -1;
}

__global__ void pagedkv_build_map(const int* __restrict__ slots,
                                  int* __restrict__ map) {
    int t = blockIdx.x * blockDim.x + threadIdx.x;
    if (t < NTOK) map[slots[t]] = t;
}

// One streaming pass over the output. i indexes float4 within one cache:
//   d4 = i & 31 (HD/4 = 32), row = i>>5, off = row & 15, h = (row>>4) & 7,
//   page = row >> 7. slot = page*16 + off.
__global__ void pagedkv_gather(const float4* __restrict__ kc,
                               const float4* __restrict__ vc,
                               const float4* __restrict__ kv,
                               const float4* __restrict__ vv,
                               const int* __restrict__ map,
                               float4* __restrict__ out) {
    long long i      = (long long)blockIdx.x * blockDim.x + threadIdx.x;
    long long stride = (long long)gridDim.x * blockDim.x;
    float4* __restrict__ outk = out;
    float4* __restrict__ outv = out + CACHE_F4;
    for (; i < CACHE_F4; i += stride) {
        const int       d4   = (int)(i & 31);
        const long long row  = i >> 5;
        const int       off  = (int)(row & 15);
        const int       h    = (int)((row >> 4) & 7);
        const long long page = row >> 7;
        const int tok = map[(page << 4) | off];
        float4 k, v;
        if (tok >= 0) {
            const long long s = ((long long)tok * NH + h) * (HD / 4) + d4;
            k = kv[s];
            v = vv[s];
        } else {
            k = kc[i];
            v = vc[i];
        }
        outk[i] = k;
        outv[i] = v;
    }
}

extern "C" void kernel_launch(void* const* d_in, const int* in_sizes, int n_in,
                              void* d_out, int out_size, void* d_ws, size_t ws_size,
                              hipStream_t stream) {
    const float4* kc    = (const float4*)d_in[0];
    const float4* vc    = (const float4*)d_in[1];
    const float4* kv    = (const float4*)d_in[2];
    const float4* vv    = (const float4*)d_in[3];
    const int*    slots = (const int*)d_in[4];
    float4* out = (float4*)d_out;
    int*    map = (int*)d_ws;   // 65536 ints = 256 KB

    pagedkv_init_map<<<NSLOT / 256, 256, 0, stream>>>(map);
    pagedkv_build_map<<<NTOK / 256, 256, 0, stream>>>(slots, map);
    pagedkv_gather<<<2048, 256, 0, stream>>>(kc, vc, kv, vv, map, out);
}

// Round 3
// 203.629 us; speedup vs baseline: 1.2348x; 1.1108x over previous
//
#include <hip/hip_runtime.h>

// PagedKVCache: out = stack([k_cache.at[page,:,off].set(k_val), same for v])
//   k_cache/v_cache: [4096, 8, 16, 128] fp32 (256 MB each)
//   k_val/v_val:     [32, 512, 8, 128] fp32  (64 MB each)
//   slot_mapping:    [32, 512] int (16384 tokens)
//   out:             [2, 4096, 8, 16, 128] fp32 (512 MB)
//
// Gather formulation (every output byte written exactly once):
//   map[slot] = token overwriting that slot, else -1 (memset 0xFF).
//   One block per page; 16 map entries staged in LDS; 16 unrolled iterations
//   stream 64 KB (K) + 64 KB (V) per page with contiguous coalesced f4
//   accesses. Branch-free pointer select; int32 indexing; nontemporal
//   loads/stores on the bulk streams.

#define NP   4096
#define NH   8
#define PG   16
#define HD   128
#define NTOK (32 * 512)
#define NSLOT (NP * PG)          // 65536
#define ROWF4 (HD / 4)           // 32
#define PAGEF4 (NH * PG * ROWF4) // 4096 float4 per page per cache

static constexpr int CACHE_F4 = NP * PAGEF4; // 16,777,216 (fits int32)

typedef float f32x4 __attribute__((ext_vector_type(4)));

__global__ void pagedkv_build_map(const int* __restrict__ slots,
                                  int* __restrict__ map) {
    int t = blockIdx.x * blockDim.x + threadIdx.x;
    if (t < NTOK) map[slots[t]] = t;
}

__global__ __launch_bounds__(256) void pagedkv_gather(
        const f32x4* __restrict__ kc,
        const f32x4* __restrict__ vc,
        const f32x4* __restrict__ kv,
        const f32x4* __restrict__ vv,
        const int* __restrict__ map,
        f32x4* __restrict__ out) {
    __shared__ int toks[PG];
    const int page = blockIdx.x;
    if (threadIdx.x < PG) toks[threadIdx.x] = map[(page << 4) + threadIdx.x];
    __syncthreads();

    const int pbase = page * PAGEF4;             // f4 index of this page
    f32x4* __restrict__ outk = out;
    f32x4* __restrict__ outv = out + CACHE_F4;

#pragma unroll
    for (int it = 0; it < PAGEF4 / 256; ++it) {  // 16 iterations
        const int i   = it * 256 + (int)threadIdx.x; // 0..4095 within page
        const int d4  = i & 31;
        const int off = (i >> 5) & 15;
        const int h   = i >> 9;
        const int tok = toks[off];
        const int gi  = pbase + i;
        // branch-free source select: token row or old cache row
        const int s = (tok * NH + h) * ROWF4 + d4;   // valid only if tok>=0
        const f32x4* sk = (tok >= 0) ? (kv + s) : (kc + gi);
        const f32x4* sv = (tok >= 0) ? (vv + s) : (vc + gi);
        f32x4 k = __builtin_nontemporal_load(sk);
        f32x4 v = __builtin_nontemporal_load(sv);
        __builtin_nontemporal_store(k, outk + gi);
        __builtin_nontemporal_store(v, outv + gi);
    }
}

extern "C" void kernel_launch(void* const* d_in, const int* in_sizes, int n_in,
                              void* d_out, int out_size, void* d_ws, size_t ws_size,
                              hipStream_t stream) {
    const f32x4* kc    = (const f32x4*)d_in[0];
    const f32x4* vc    = (const f32x4*)d_in[1];
    const f32x4* kv    = (const f32x4*)d_in[2];
    const f32x4* vv    = (const f32x4*)d_in[3];
    const int*   slots = (const int*)d_in[4];
    f32x4* out = (f32x4*)d_out;
    int*   map = (int*)d_ws;   // 65536 ints = 256 KB

    hipMemsetAsync(map, 0xFF, NSLOT * sizeof(int), stream);   // map[:] = -1
    pagedkv_build_map<<<NTOK / 256, 256, 0, stream>>>(slots, map);
    pagedkv_gather<<<NP, 256, 0, stream>>>(kc, vc, kv, vv, map, out);
}